// Round 3
// baseline (1982.902 us; speedup 1.0000x reference)
//
#include <hip/hip_runtime.h>

#define BATCH 256
#define TSTEPS 4096
#define HID 136
#define HPAD 160      // k padded to 8 chunks of 20 floats (80 B, 16B-aligned starts)
#define RPAD 160      // rows padded to 32 groups x 5
#define ODIM 68
#define RPT 5         // rows per thread
#define CHUNK 20      // k-floats per thread (5 x ds_read_b128)
#define THREADS 256   // 4 waves, exactly 1 per SIMD

__device__ __forceinline__ float fast_tanh(float z) {
    float az = fabsf(z);
    float e = __expf(-2.0f * az);
    float r = (1.0f - e) * __builtin_amdgcn_rcpf(1.0f + e);
    return copysignf(r, z);
}

// quad butterfly stages on the VALU pipe (DPP quad_perm)
__device__ __forceinline__ float dpp_xor1_add(float x) {   // + value at lane^1
    int y = __builtin_amdgcn_update_dpp(0, __float_as_int(x), 0xB1, 0xF, 0xF, false);
    return x + __int_as_float(y);
}
__device__ __forceinline__ float dpp_xor2_add(float x) {   // + value at lane^2
    int y = __builtin_amdgcn_update_dpp(0, __float_as_int(x), 0x4E, 0xF, 0xF, false);
    return x + __int_as_float(y);
}

// One recurrence step: read HR, write HW. All LDS base addresses loop-invariant.
// Each thread: 5 ds_read_b128 -> 100 FMAs (5 rows x 20 k) -> butterfly over 8
// lanes -> lane ks<5 finishes row 5g+ks (z, tanh) -> one b32 write.
#define RNN_STEP(HR, HW, T)                                                    \
    {                                                                          \
        float2 xv = *(const float2*)(xs + 2 * (T));                            \
        const float4* hp = (const float4*)((HR) + k0);                         \
        float a0 = 0.f, a1 = 0.f, a2 = 0.f, a3 = 0.f, a4 = 0.f;                \
        _Pragma("unroll")                                                      \
        for (int i = 0; i < CHUNK / 4; ++i) {                                  \
            float4 h4 = hp[i];                                                 \
            a0 = fmaf(h4.x, wm[0][4*i+0], a0);                                 \
            a0 = fmaf(h4.y, wm[0][4*i+1], a0);                                 \
            a0 = fmaf(h4.z, wm[0][4*i+2], a0);                                 \
            a0 = fmaf(h4.w, wm[0][4*i+3], a0);                                 \
            a1 = fmaf(h4.x, wm[1][4*i+0], a1);                                 \
            a1 = fmaf(h4.y, wm[1][4*i+1], a1);                                 \
            a1 = fmaf(h4.z, wm[1][4*i+2], a1);                                 \
            a1 = fmaf(h4.w, wm[1][4*i+3], a1);                                 \
            a2 = fmaf(h4.x, wm[2][4*i+0], a2);                                 \
            a2 = fmaf(h4.y, wm[2][4*i+1], a2);                                 \
            a2 = fmaf(h4.z, wm[2][4*i+2], a2);                                 \
            a2 = fmaf(h4.w, wm[2][4*i+3], a2);                                 \
            a3 = fmaf(h4.x, wm[3][4*i+0], a3);                                 \
            a3 = fmaf(h4.y, wm[3][4*i+1], a3);                                 \
            a3 = fmaf(h4.z, wm[3][4*i+2], a3);                                 \
            a3 = fmaf(h4.w, wm[3][4*i+3], a3);                                 \
            a4 = fmaf(h4.x, wm[4][4*i+0], a4);                                 \
            a4 = fmaf(h4.y, wm[4][4*i+1], a4);                                 \
            a4 = fmaf(h4.z, wm[4][4*i+2], a4);                                 \
            a4 = fmaf(h4.w, wm[4][4*i+3], a4);                                 \
        }                                                                      \
        a0 = dpp_xor1_add(a0); a0 = dpp_xor2_add(a0); a0 += __shfl_xor(a0, 4); \
        a1 = dpp_xor1_add(a1); a1 = dpp_xor2_add(a1); a1 += __shfl_xor(a1, 4); \
        a2 = dpp_xor1_add(a2); a2 = dpp_xor2_add(a2); a2 += __shfl_xor(a2, 4); \
        a3 = dpp_xor1_add(a3); a3 = dpp_xor2_add(a3); a3 += __shfl_xor(a3, 4); \
        a4 = dpp_xor1_add(a4); a4 = dpp_xor2_add(a4); a4 += __shfl_xor(a4, 4); \
        float zsum = (ks == 0) ? a0 : (ks == 1) ? a1 : (ks == 2) ? a2          \
                     : (ks == 3) ? a3 : a4;                                    \
        float z = fmaf(xv.x, wih0, fmaf(xv.y, wih1, bias)) + zsum;             \
        float th = fast_tanh(z);                                               \
        if (ks < RPT) (HW)[wrow] = th;                                         \
    }

__global__ __launch_bounds__(THREADS)
void rnn_fused_kernel(const float* __restrict__ x,
                      const float* __restrict__ W_ih,
                      const float* __restrict__ W_hh,
                      const float* __restrict__ b_ih,
                      const float* __restrict__ b_hh,
                      const float* __restrict__ W_fc,
                      const float* __restrict__ b_fc,
                      float* __restrict__ out)
{
    __shared__ __align__(16) float xs[TSTEPS * 2];   // 32 KB: x[b,:,:]
    __shared__ __align__(16) float hA[RPAD];
    __shared__ __align__(16) float hB[RPAD];

    const int b   = blockIdx.x;
    const int tid = threadIdx.x;
    const int g   = tid >> 3;      // row-group 0..31 (rows 5g..5g+4)
    const int ks  = tid & 7;       // k-split lane within group
    const int k0  = ks * CHUNK;    // k-chunk start (80 B aligned)

    // ---- persistent W_hh block in registers: 5 rows x 20 k = 100 VGPR ----
    float wm[RPT][CHUNK];
#pragma unroll
    for (int r = 0; r < RPT; ++r) {
        int row = g * RPT + r;
#pragma unroll
        for (int i = 0; i < CHUNK; ++i) {
            int k = k0 + i;
            wm[r][i] = (row < HID && k < HID) ? W_hh[row * HID + k] : 0.0f;
        }
    }
    // per-lane output row (lane ks<5 finishes row 5g+ks)
    const int wrow  = g * RPT + ks;
    const bool rv   = (ks < RPT) && (wrow < HID);
    const float wih0 = rv ? W_ih[wrow * 2 + 0] : 0.0f;
    const float wih1 = rv ? W_ih[wrow * 2 + 1] : 0.0f;
    const float bias = rv ? (b_ih[wrow] + b_hh[wrow]) : 0.0f;

    // ---- stage x[b] into LDS (coalesced float4), zero h buffers ----
    {
        const float4* xg = (const float4*)(x + (size_t)b * (TSTEPS * 2));
        float4* xl = (float4*)xs;
#pragma unroll
        for (int i = 0; i < TSTEPS * 2 / 4 / THREADS; ++i)
            xl[i * THREADS + tid] = xg[i * THREADS + tid];
    }
    for (int i = tid; i < RPAD; i += THREADS) { hA[i] = 0.0f; hB[i] = 0.0f; }
    __syncthreads();

    // ---- recurrence, unrolled x2 (fixed buffers), 1 barrier per step ----
    for (int t = 0; t < TSTEPS; t += 2) {
        RNN_STEP(hA, hB, t);
        __syncthreads();
        RNN_STEP(hB, hA, t + 1);
        __syncthreads();
    }
    // TSTEPS even -> final h in hA

    // ---- final head (once): out[b][o] = h . W_fc[o,:] + b_fc[o] ----
    if (tid < ODIM * 2) {
        int o    = tid >> 1;
        int half = tid & 1;
        int kb   = half * (HID / 2);
        float p = 0.f;
#pragma unroll
        for (int k = 0; k < HID / 2; ++k)
            p = fmaf(hA[kb + k], W_fc[o * HID + kb + k], p);
        p += __shfl_xor(p, 1);
        if (half == 0) out[b * ODIM + o] = p + b_fc[o];
    }
}

extern "C" void kernel_launch(void* const* d_in, const int* in_sizes, int n_in,
                              void* d_out, int out_size, void* d_ws, size_t ws_size,
                              hipStream_t stream) {
    const float* x    = (const float*)d_in[0];
    const float* W_ih = (const float*)d_in[1];
    const float* W_hh = (const float*)d_in[2];
    const float* b_ih = (const float*)d_in[3];
    const float* b_hh = (const float*)d_in[4];
    const float* W_fc = (const float*)d_in[5];
    const float* b_fc = (const float*)d_in[6];
    float* out = (float*)d_out;

    rnn_fused_kernel<<<BATCH, THREADS, 0, stream>>>(x, W_ih, W_hh, b_ih, b_hh,
                                                    W_fc, b_fc, out);
}

// Round 5
// 1631.294 us; speedup vs baseline: 1.2155x; 1.2155x over previous
//
#include <hip/hip_runtime.h>

#define BATCH 256
#define TSTEPS 4096
#define HID 136
#define HPAD 144      // k padded: 16 lanes x 9 floats
#define ODIM 68
#define RPT 4         // rows per thread
#define NGRP 34       // row groups (34 x 4 = 136 rows exactly)
#define SPL 16        // k-split lanes per group
#define THREADS (NGRP * SPL)   // 544

__device__ __forceinline__ float fast_tanh(float z) {
    float az = fabsf(z);
    float e = __expf(-2.0f * az);
    float r = (1.0f - e) * __builtin_amdgcn_rcpf(1.0f + e);
    return copysignf(r, z);
}

// DPP add on the VALU pipe (no LDS traffic); ctrl must be compile-time const
template <int CTRL>
__device__ __forceinline__ float dpp_add(float x) {
    int y = __builtin_amdgcn_update_dpp(0, __float_as_int(x), CTRL, 0xF, 0xF, false);
    return x + __int_as_float(y);
}
// reduce over the 16 lanes of a row: after this, ALL 16 lanes hold the sum
__device__ __forceinline__ float reduce16(float x) {
    x = dpp_add<0xB1>(x);    // quad_perm xor1
    x = dpp_add<0x4E>(x);    // quad_perm xor2
    x = dpp_add<0x124>(x);   // row_ror:4
    x = dpp_add<0x128>(x);   // row_ror:8
    return x;
}

// One step: read HR, write HW. Per thread: 3 DS reads (2xb128 + b32),
// 36 FMA (4 rows x 9 k), 16 DPP-adds, tanh on all lanes, 1 predicated write.
#define RNN_STEP(HR, HW, T)                                                    \
    {                                                                          \
        float2 xv = *(const float2*)(xs + 2 * (T));                            \
        float4 hlo = *(const float4*)((HR) + 4 * ks);                          \
        float4 hhi = *(const float4*)((HR) + 64 + 4 * ks);                     \
        float  hex = (HR)[128 + ks];                                           \
        float a0, a1, a2, a3;                                                  \
        a0 = hlo.x * wm[0][0];                                                 \
        a1 = hlo.x * wm[1][0];                                                 \
        a2 = hlo.x * wm[2][0];                                                 \
        a3 = hlo.x * wm[3][0];                                                 \
        a0 = fmaf(hlo.y, wm[0][1], a0); a1 = fmaf(hlo.y, wm[1][1], a1);        \
        a2 = fmaf(hlo.y, wm[2][1], a2); a3 = fmaf(hlo.y, wm[3][1], a3);        \
        a0 = fmaf(hlo.z, wm[0][2], a0); a1 = fmaf(hlo.z, wm[1][2], a1);        \
        a2 = fmaf(hlo.z, wm[2][2], a2); a3 = fmaf(hlo.z, wm[3][2], a3);        \
        a0 = fmaf(hlo.w, wm[0][3], a0); a1 = fmaf(hlo.w, wm[1][3], a1);        \
        a2 = fmaf(hlo.w, wm[2][3], a2); a3 = fmaf(hlo.w, wm[3][3], a3);        \
        a0 = fmaf(hhi.x, wm[0][4], a0); a1 = fmaf(hhi.x, wm[1][4], a1);        \
        a2 = fmaf(hhi.x, wm[2][4], a2); a3 = fmaf(hhi.x, wm[3][4], a3);        \
        a0 = fmaf(hhi.y, wm[0][5], a0); a1 = fmaf(hhi.y, wm[1][5], a1);        \
        a2 = fmaf(hhi.y, wm[2][5], a2); a3 = fmaf(hhi.y, wm[3][5], a3);        \
        a0 = fmaf(hhi.z, wm[0][6], a0); a1 = fmaf(hhi.z, wm[1][6], a1);        \
        a2 = fmaf(hhi.z, wm[2][6], a2); a3 = fmaf(hhi.z, wm[3][6], a3);        \
        a0 = fmaf(hhi.w, wm[0][7], a0); a1 = fmaf(hhi.w, wm[1][7], a1);        \
        a2 = fmaf(hhi.w, wm[2][7], a2); a3 = fmaf(hhi.w, wm[3][7], a3);        \
        a0 = fmaf(hex, wm[0][8], a0);   a1 = fmaf(hex, wm[1][8], a1);          \
        a2 = fmaf(hex, wm[2][8], a2);   a3 = fmaf(hex, wm[3][8], a3);          \
        a0 = reduce16(a0);                                                     \
        a1 = reduce16(a1);                                                     \
        a2 = reduce16(a2);                                                     \
        a3 = reduce16(a3);                                                     \
        float sum = (ks & 2) ? ((ks & 1) ? a3 : a2) : ((ks & 1) ? a1 : a0);    \
        float z = fmaf(xv.x, wih0, fmaf(xv.y, wih1, bias)) + sum;              \
        float th = fast_tanh(z);                                               \
        if (ks < RPT) (HW)[wrow] = th;                                         \
    }

__global__ __launch_bounds__(THREADS)
void rnn_fused_kernel(const float* __restrict__ x,
                      const float* __restrict__ W_ih,
                      const float* __restrict__ W_hh,
                      const float* __restrict__ b_ih,
                      const float* __restrict__ b_hh,
                      const float* __restrict__ W_fc,
                      const float* __restrict__ b_fc,
                      float* __restrict__ out)
{
    __shared__ __align__(16) float xs[TSTEPS * 2];   // 32 KB: x[b,:,:]
    __shared__ __align__(16) float hA[HPAD];
    __shared__ __align__(16) float hB[HPAD];

    const int b   = blockIdx.x;
    const int tid = threadIdx.x;
    const int g   = tid >> 4;      // row group 0..33 (rows 4g..4g+3)
    const int ks  = tid & 15;      // k-lane within group (= lane%16)

    // k map for lane ks: i=0..3 -> 4ks+i ; i=4..7 -> 64+4ks+(i-4) ; i=8 -> 128+ks
    // ---- persistent W_hh block in registers: 4 rows x 9 k = 36 VGPR ----
    float wm[RPT][9];
#pragma unroll
    for (int r = 0; r < RPT; ++r) {
        const int row = g * RPT + r;
#pragma unroll
        for (int i = 0; i < 9; ++i) {
            const int k = (i < 4) ? (4 * ks + i)
                        : (i < 8) ? (64 + 4 * ks + (i - 4))
                                  : (128 + ks);
            wm[r][i] = (k < HID) ? W_hh[row * HID + k] : 0.0f;
        }
    }
    // per-lane finished row (lanes ks<4 write row 4g+ks; all lanes compute)
    const int wrow = g * RPT + (ks & 3);
    const float wih0 = W_ih[wrow * 2 + 0];
    const float wih1 = W_ih[wrow * 2 + 1];
    const float bias = b_ih[wrow] + b_hh[wrow];

    // ---- stage x[b] into LDS (coalesced float4); zero h buffers ----
    {
        const float4* xg = (const float4*)(x + (size_t)b * (TSTEPS * 2));
        float4* xl = (float4*)xs;
        for (int i = tid; i < TSTEPS * 2 / 4; i += THREADS) xl[i] = xg[i];
    }
    for (int i = tid; i < HPAD; i += THREADS) { hA[i] = 0.0f; hB[i] = 0.0f; }
    __syncthreads();

    // ---- recurrence, unrolled x2 (fixed buffers), 1 barrier per step ----
    for (int t = 0; t < TSTEPS; t += 2) {
        RNN_STEP(hA, hB, t);
        __syncthreads();
        RNN_STEP(hB, hA, t + 1);
        __syncthreads();
    }
    // TSTEPS even -> final h in hA

    // ---- final head: out[b][o] = h . W_fc[o,:] + b_fc[o] ----
    if (tid < ODIM * 2) {
        const int o    = tid >> 1;
        const int half = tid & 1;
        const int kb   = half * (HID / 2);
        float p = 0.f;
#pragma unroll
        for (int k = 0; k < HID / 2; ++k)
            p = fmaf(hA[kb + k], W_fc[o * HID + kb + k], p);
        p = dpp_add<0xB1>(p);            // + partner half
        if (half == 0) out[b * ODIM + o] = p + b_fc[o];
    }
}

extern "C" void kernel_launch(void* const* d_in, const int* in_sizes, int n_in,
                              void* d_out, int out_size, void* d_ws, size_t ws_size,
                              hipStream_t stream) {
    const float* x    = (const float*)d_in[0];
    const float* W_ih = (const float*)d_in[1];
    const float* W_hh = (const float*)d_in[2];
    const float* b_ih = (const float*)d_in[3];
    const float* b_hh = (const float*)d_in[4];
    const float* W_fc = (const float*)d_in[5];
    const float* b_fc = (const float*)d_in[6];
    float* out = (float*)d_out;

    rnn_fused_kernel<<<BATCH, THREADS, 0, stream>>>(x, W_ih, W_hh, b_ih, b_hh,
                                                    W_fc, b_fc, out);
}

// Round 6
// 1355.795 us; speedup vs baseline: 1.4625x; 1.2032x over previous
//
#include <hip/hip_runtime.h>

#define BATCH 256
#define TSTEPS 4096
#define HID 136
#define HPAD 144      // h padded to 144 f16 (rows 136..143 always zero)
#define ODIM 68
#define THREADS 512   // 8 waves, exactly 2 per SIMD

typedef _Float16 h2 __attribute__((ext_vector_type(2)));

__device__ __forceinline__ float fast_tanh(float z) {
    float az = fabsf(z);
    float e = __expf(-2.0f * az);
    float r = (1.0f - e) * __builtin_amdgcn_rcpf(1.0f + e);
    return copysignf(r, z);
}

// DPP add on the VALU pipe; ctrl is compile-time const (R5-proven path)
template <int CTRL>
__device__ __forceinline__ float dpp_add(float x) {
    int y = __builtin_amdgcn_update_dpp(0, __float_as_int(x), CTRL, 0xF, 0xF, false);
    return x + __int_as_float(y);
}
// butterfly over 8 consecutive lanes: after this all 8 hold the full sum
__device__ __forceinline__ float reduce8(float x) {
    x = dpp_add<0xB1>(x);    // quad_perm xor1
    x = dpp_add<0x4E>(x);    // quad_perm xor2
    x = dpp_add<0x141>(x);   // row_half_mirror (i^7 within 8)
    return x;
}

__device__ __forceinline__ h2 bc_h2(unsigned int u) {
    union { unsigned int u; h2 h; } c; c.u = u; return c.h;
}

// One step: read HR (f16 h), write HW. Per thread: 3 DS reads (2xb128+b32),
// 27 fdot2 (2 main rows + 1 extra row, 9 pairs each), 9 DPP-adds, tanh, write.
#define RNN_STEP(HR, HW, T)                                                    \
    {                                                                          \
        float2 xv = *(const float2*)(xs + 2 * (T));                            \
        uint4 u0 = *(const uint4*)((HR) + 16 * ks);                            \
        uint4 u1 = *(const uint4*)((HR) + 16 * ks + 8);                        \
        unsigned int ut = *(const unsigned int*)((HR) + 128 + 2 * ks);         \
        float sa = 0.f, sb = 0.f, se = 0.f;                                    \
        h2 hq;                                                                 \
        hq = bc_h2(u0.x);                                                      \
        sa = __builtin_amdgcn_fdot2(hq, wqa[0], sa, false);                    \
        sb = __builtin_amdgcn_fdot2(hq, wqb[0], sb, false);                    \
        se = __builtin_amdgcn_fdot2(hq, wqe[0], se, false);                    \
        hq = bc_h2(u0.y);                                                      \
        sa = __builtin_amdgcn_fdot2(hq, wqa[1], sa, false);                    \
        sb = __builtin_amdgcn_fdot2(hq, wqb[1], sb, false);                    \
        se = __builtin_amdgcn_fdot2(hq, wqe[1], se, false);                    \
        hq = bc_h2(u0.z);                                                      \
        sa = __builtin_amdgcn_fdot2(hq, wqa[2], sa, false);                    \
        sb = __builtin_amdgcn_fdot2(hq, wqb[2], sb, false);                    \
        se = __builtin_amdgcn_fdot2(hq, wqe[2], se, false);                    \
        hq = bc_h2(u0.w);                                                      \
        sa = __builtin_amdgcn_fdot2(hq, wqa[3], sa, false);                    \
        sb = __builtin_amdgcn_fdot2(hq, wqb[3], sb, false);                    \
        se = __builtin_amdgcn_fdot2(hq, wqe[3], se, false);                    \
        hq = bc_h2(u1.x);                                                      \
        sa = __builtin_amdgcn_fdot2(hq, wqa[4], sa, false);                    \
        sb = __builtin_amdgcn_fdot2(hq, wqb[4], sb, false);                    \
        se = __builtin_amdgcn_fdot2(hq, wqe[4], se, false);                    \
        hq = bc_h2(u1.y);                                                      \
        sa = __builtin_amdgcn_fdot2(hq, wqa[5], sa, false);                    \
        sb = __builtin_amdgcn_fdot2(hq, wqb[5], sb, false);                    \
        se = __builtin_amdgcn_fdot2(hq, wqe[5], se, false);                    \
        hq = bc_h2(u1.z);                                                      \
        sa = __builtin_amdgcn_fdot2(hq, wqa[6], sa, false);                    \
        sb = __builtin_amdgcn_fdot2(hq, wqb[6], sb, false);                    \
        se = __builtin_amdgcn_fdot2(hq, wqe[6], se, false);                    \
        hq = bc_h2(u1.w);                                                      \
        sa = __builtin_amdgcn_fdot2(hq, wqa[7], sa, false);                    \
        sb = __builtin_amdgcn_fdot2(hq, wqb[7], sb, false);                    \
        se = __builtin_amdgcn_fdot2(hq, wqe[7], se, false);                    \
        hq = bc_h2(ut);                                                        \
        sa = __builtin_amdgcn_fdot2(hq, wqa[8], sa, false);                    \
        sb = __builtin_amdgcn_fdot2(hq, wqb[8], sb, false);                    \
        se = __builtin_amdgcn_fdot2(hq, wqe[8], se, false);                    \
        sa = reduce8(sa);                                                      \
        sb = reduce8(sb);                                                      \
        se = reduce8(se);                                                      \
        float zsum = (ks == 0) ? sa : (ks == 1) ? sb : se;                     \
        float z = fmaf(xv.x, wih0, fmaf(xv.y, wih1, bias)) + zsum;             \
        float th = fast_tanh(z);                                               \
        if (ks < 3) (HW)[prow] = (_Float16)th;                                 \
    }

__global__ __launch_bounds__(THREADS)
void rnn_fused_kernel(const float* __restrict__ x,
                      const float* __restrict__ W_ih,
                      const float* __restrict__ W_hh,
                      const float* __restrict__ b_ih,
                      const float* __restrict__ b_hh,
                      const float* __restrict__ W_fc,
                      const float* __restrict__ b_fc,
                      float* __restrict__ out)
{
    __shared__ __align__(16) float xs[TSTEPS * 2];     // 32 KB: x[b,:,:]
    __shared__ __align__(16) _Float16 hA[HPAD];
    __shared__ __align__(16) _Float16 hB[HPAD];

    const int b   = blockIdx.x;
    const int tid = threadIdx.x;
    const int g   = tid >> 3;      // row group 0..63 (main rows 2g, 2g+1)
    const int ks  = tid & 7;       // k-lane within group
    const int wv  = tid >> 6;      // wave 0..7 -> extra row 128+wv

    // k map for lane ks: q=0..7 -> k = 16*ks + 2q (+pair), q=8 -> k = 128 + 2*ks
    const int rowA = 2 * g;
    const int rowB = 2 * g + 1;
    const int erow = 128 + wv;     // 128..135, always valid

    h2 wqa[9], wqb[9], wqe[9];
#pragma unroll
    for (int q = 0; q < 9; ++q) {
        const int k = (q < 8) ? (16 * ks + 2 * q) : (128 + 2 * ks);
        const float a0 = (k     < HID) ? W_hh[rowA * HID + k]     : 0.0f;
        const float a1 = (k + 1 < HID) ? W_hh[rowA * HID + k + 1] : 0.0f;
        const float b0 = (k     < HID) ? W_hh[rowB * HID + k]     : 0.0f;
        const float b1 = (k + 1 < HID) ? W_hh[rowB * HID + k + 1] : 0.0f;
        const float e0 = (k     < HID) ? W_hh[erow * HID + k]     : 0.0f;
        const float e1 = (k + 1 < HID) ? W_hh[erow * HID + k + 1] : 0.0f;
        wqa[q] = h2{(_Float16)a0, (_Float16)a1};
        wqb[q] = h2{(_Float16)b0, (_Float16)b1};
        wqe[q] = h2{(_Float16)e0, (_Float16)e1};
    }
    // per-lane finished row: ks==0 -> rowA, ks==1 -> rowB, ks==2 -> erow
    const int prow = (ks == 0) ? rowA : (ks == 1) ? rowB : (ks == 2) ? erow : rowA;
    const float wih0 = W_ih[prow * 2 + 0];
    const float wih1 = W_ih[prow * 2 + 1];
    const float bias = b_ih[prow] + b_hh[prow];

    // ---- stage x[b] into LDS (coalesced float4); zero h buffers ----
    {
        const float4* xg = (const float4*)(x + (size_t)b * (TSTEPS * 2));
        float4* xl = (float4*)xs;
#pragma unroll
        for (int i = 0; i < TSTEPS * 2 / 4 / THREADS; ++i)
            xl[i * THREADS + tid] = xg[i * THREADS + tid];
    }
    for (int i = tid; i < HPAD; i += THREADS) {
        hA[i] = (_Float16)0.f;
        hB[i] = (_Float16)0.f;
    }
    __syncthreads();

    // ---- recurrence, unrolled x2 (fixed buffers), 1 barrier per step ----
    for (int t = 0; t < TSTEPS; t += 2) {
        RNN_STEP(hA, hB, t);
        __syncthreads();
        RNN_STEP(hB, hA, t + 1);
        __syncthreads();
    }
    // TSTEPS even -> final h in hA

    // ---- final head: out[b][o] = h . W_fc[o,:] + b_fc[o] ----
    if (tid < ODIM * 2) {
        const int o    = tid >> 1;
        const int half = tid & 1;
        const int kb   = half * (HID / 2);
        float p = 0.f;
#pragma unroll
        for (int k = 0; k < HID / 2; ++k)
            p = fmaf((float)hA[kb + k], W_fc[o * HID + kb + k], p);
        p = dpp_add<0xB1>(p);            // + partner half (lane xor 1)
        if (half == 0) out[b * ODIM + o] = p + b_fc[o];
    }
}

extern "C" void kernel_launch(void* const* d_in, const int* in_sizes, int n_in,
                              void* d_out, int out_size, void* d_ws, size_t ws_size,
                              hipStream_t stream) {
    const float* x    = (const float*)d_in[0];
    const float* W_ih = (const float*)d_in[1];
    const float* W_hh = (const float*)d_in[2];
    const float* b_ih = (const float*)d_in[3];
    const float* b_hh = (const float*)d_in[4];
    const float* W_fc = (const float*)d_in[5];
    const float* b_fc = (const float*)d_in[6];
    float* out = (float*)d_out;

    rnn_fused_kernel<<<BATCH, THREADS, 0, stream>>>(x, W_ih, W_hh, b_ih, b_hh,
                                                    W_fc, b_fc, out);
}